// Round 14
// baseline (1648.860 us; speedup 1.0000x reference)
//
#include <hip/hip_runtime.h>
#include <hip/hip_bf16.h>

#define TSEQ 256
#define NB 16
#define DD 512
#define HHH 512
#define VV 32000

typedef __attribute__((ext_vector_type(4))) float floatx4;
typedef __attribute__((ext_vector_type(8))) __bf16 bf16x8;
typedef __attribute__((ext_vector_type(4))) unsigned int uintx4;

__device__ __forceinline__ float sigmoidf_(float x) { return 1.f / (1.f + __expf(-x)); }
__device__ __forceinline__ float tanhf_(float x) {
  float e = __expf(2.f * x);
  return (e - 1.f) / (e + 1.f);
}

__device__ __forceinline__ unsigned short f2bf(float f) {
  __hip_bfloat16 h = __float2bfloat16(f);
  return __builtin_bit_cast(unsigned short, h);
}
__device__ __forceinline__ float bf2f(unsigned short u) {
  unsigned int v = ((unsigned int)u) << 16;
  return __builtin_bit_cast(float, v);
}

__device__ __forceinline__ void gld_lds16(const void* g, void* l) {
  __builtin_amdgcn_global_load_lds((const __attribute__((address_space(1))) void*)g,
                                   (__attribute__((address_space(3))) void*)l, 16, 0, 0);
}

// ---------------- Generic bf16 MFMA GEMM: C = A(MxK) * Bt(NxK)^T (+bias)(+tanh) ----------------
template <int OUT_BF16, int HAS_BIAS, int ACT_TANH>
__global__ __launch_bounds__(256, 2) void gemm_bt(
    const unsigned short* __restrict__ A, const unsigned short* __restrict__ Bt,
    void* __restrict__ Cv, const float* __restrict__ bias,
    int K, int ldc, long sA, long sB, long sC) {
  __shared__ unsigned short As[128 * 32];
  __shared__ unsigned short Bs[128 * 32];
  const int tid = threadIdx.x;
  const int wave = tid >> 6, lane = tid & 63;
  const int lrow = lane & 15, lkg = lane >> 4;
  const int wr = wave >> 1, wc = wave & 1;
  const int bz = blockIdx.z;

  const unsigned short* Ab = A + (long)bz * sA + (long)blockIdx.y * 128 * K;
  const unsigned short* Bb = Bt + (long)bz * sB + (long)blockIdx.x * 128 * K;

  const int srow = tid >> 2;
  const int scg = (tid & 3) ^ ((tid >> 3) & 3);
  const long srcOff = (long)srow * K + scg * 8;

  char* aDst = (char*)As + wave * 1024;
  char* bDst = (char*)Bs + wave * 1024;

  floatx4 acc[4][4];
#pragma unroll
  for (int i = 0; i < 4; ++i)
#pragma unroll
    for (int j = 0; j < 4; ++j) acc[i][j] = floatx4{0.f, 0.f, 0.f, 0.f};

  for (int k0 = 0; k0 < K; k0 += 32) {
    gld_lds16(Ab + srcOff + k0, aDst);
    gld_lds16(Ab + srcOff + (long)64 * K + k0, aDst + 4096);
    gld_lds16(Bb + srcOff + k0, bDst);
    gld_lds16(Bb + srcOff + (long)64 * K + k0, bDst + 4096);
    __syncthreads();
    bf16x8 af[4], bfr[4];
#pragma unroll
    for (int mi = 0; mi < 4; ++mi) {
      int R = wr * 64 + mi * 16 + lrow;
      int cg = lkg ^ ((R >> 1) & 3);
      af[mi] = *(const bf16x8*)((const char*)As + R * 64 + cg * 16);
    }
#pragma unroll
    for (int ni = 0; ni < 4; ++ni) {
      int R = wc * 64 + ni * 16 + lrow;
      int cg = lkg ^ ((R >> 1) & 3);
      bfr[ni] = *(const bf16x8*)((const char*)Bs + R * 64 + cg * 16);
    }
#pragma unroll
    for (int mi = 0; mi < 4; ++mi)
#pragma unroll
      for (int ni = 0; ni < 4; ++ni)
        acc[mi][ni] = __builtin_amdgcn_mfma_f32_16x16x32_bf16(af[mi], bfr[ni], acc[mi][ni], 0, 0, 0);
    __syncthreads();
  }

  const int mBase = blockIdx.y * 128 + wr * 64 + lkg * 4;
  const int nBase = blockIdx.x * 128 + wc * 64 + lrow;
#pragma unroll
  for (int ni = 0; ni < 4; ++ni) {
    int n = nBase + ni * 16;
    float bv = HAS_BIAS ? bias[n] : 0.f;
#pragma unroll
    for (int mi = 0; mi < 4; ++mi) {
      int m = mBase + mi * 16;
#pragma unroll
      for (int r = 0; r < 4; ++r) {
        float v = acc[mi][ni][r] + bv;
        if (ACT_TANH) v = tanhf(v);
        if (OUT_BF16)
          ((unsigned short*)Cv)[(long)bz * sC + (long)(m + r) * ldc + n] = f2bf(v);
        else
          ((float*)Cv)[(long)bz * sC + (long)(m + r) * ldc + n] = v;
      }
    }
  }
}

// ---------------- transpose + convert to bf16: out[n][k] = in[k][n] ----------------
__device__ __forceinline__ float ldval(const float* p) { return *p; }
__device__ __forceinline__ float ldval(const unsigned short* p) { return bf2f(*p); }

template <typename TIN>
__global__ __launch_bounds__(256) void transpose_bf16(
    const TIN* __restrict__ in, unsigned short* __restrict__ out,
    int Kdim, int Ndim, int ldout, long sIn, long sOut) {
  __shared__ float tile[32][33];
  const int bz = blockIdx.z;
  in += (long)bz * sIn;
  out += (long)bz * sOut;
  int n0 = blockIdx.x * 32, k0 = blockIdx.y * 32;
  int tx = threadIdx.x & 31, ty = threadIdx.x >> 5;
#pragma unroll
  for (int j = 0; j < 4; ++j) {
    int k = k0 + ty + j * 8;
    tile[ty + j * 8][tx] = ldval(in + (long)k * Ndim + n0 + tx);
  }
  __syncthreads();
#pragma unroll
  for (int j = 0; j < 4; ++j) {
    int n = n0 + ty + j * 8;
    out[(long)n * ldout + k0 + tx] = f2bf(tile[tx][ty + j * 8]);
  }
}

// ---------------- fused weight transposes (6 jobs in one dispatch) ----------------
__global__ __launch_bounds__(256) void transpose_all(
    const float* __restrict__ Wp, unsigned short* __restrict__ WpT,
    const float* __restrict__ Wc, unsigned short* __restrict__ WcT,
    const float* __restrict__ Wih0, unsigned short* __restrict__ Wih0T,
    const float* __restrict__ Whh0, unsigned short* __restrict__ Whh0T,
    const float* __restrict__ Wih1, const float* __restrict__ Whh1,
    unsigned short* __restrict__ W1T) {
  __shared__ float tile[32][33];
  int id = blockIdx.x;
  const float* in;
  unsigned short* out;
  int Ndim, ldout, bx, by;
  if (id < 16000) {            // Wp (512 x 32000) -> WpT (32000 x 512)
    in = Wp; out = WpT; Ndim = VV; ldout = 512;
    bx = id % 1000; by = id / 1000;
  } else if (id < 16512) {     // Wc (1024 x 512) -> WcT (512 x 1024)
    id -= 16000;
    in = Wc; out = WcT; Ndim = 512; ldout = 1024;
    bx = id % 16; by = id / 16;
  } else if (id < 17536) {     // Wih0 (512 x 2048) -> Wih0T (2048 x 512)
    id -= 16512;
    in = Wih0; out = Wih0T; Ndim = 2048; ldout = 512;
    bx = id % 64; by = id / 64;
  } else if (id < 18560) {     // Whh0 -> Whh0T
    id -= 17536;
    in = Whh0; out = Whh0T; Ndim = 2048; ldout = 512;
    bx = id % 64; by = id / 64;
  } else if (id < 19584) {     // Wih1 -> W1T[:, 0:512]
    id -= 18560;
    in = Wih1; out = W1T; Ndim = 2048; ldout = 1024;
    bx = id % 64; by = id / 64;
  } else {                     // Whh1 -> W1T[:, 512:1024]
    id -= 19584;
    in = Whh1; out = W1T + 512; Ndim = 2048; ldout = 1024;
    bx = id % 64; by = id / 64;
  }
  int n0 = bx * 32, k0 = by * 32;
  int tx = threadIdx.x & 31, ty = threadIdx.x >> 5;
#pragma unroll
  for (int j = 0; j < 4; ++j) {
    int k = k0 + ty + j * 8;
    tile[ty + j * 8][tx] = in[(long)k * Ndim + n0 + tx];
  }
  __syncthreads();
#pragma unroll
  for (int j = 0; j < 4; ++j) {
    int n = n0 + ty + j * 8;
    out[(long)n * ldout + k0 + tx] = f2bf(tile[tx][ty + j * 8]);
  }
}

// ---------------- embedding gather -> bf16, rows (t*16+b) ----------------
__global__ __launch_bounds__(128) void embed_gather(
    const int* __restrict__ tok, const float* __restrict__ emb, unsigned short* __restrict__ x) {
  int rid = blockIdx.x;  // t*16 + b
  int t = rid >> 4, b = rid & 15;
  int tokv = tok[b * 257 + t];
  const float* er = emb + (long)tokv * DD;
  int d = threadIdx.x * 4;
  float4 v = *(const float4*)(er + d);
  unsigned short* xp = x + (long)rid * DD + d;
  xp[0] = f2bf(v.x);
  xp[1] = f2bf(v.y);
  xp[2] = f2bf(v.z);
  xp[3] = f2bf(v.w);
}

// ================= EPOCH-EMBEDDED MAILBOX LSTM =================
// R11/R13 structure. One change vs R13: L1's two dependency polls (mb0[t+1],
// mb1[t]) are merged into ONE concurrent 16-unit volley (poll_scatter2) --
// saves a full serialized MALL round per L1 step. No canary, no drain (R12's
// regression). L0 path untouched. Detection IS the fetch (epoch in-band).

__device__ __forceinline__ void poll_scatter(const unsigned int* mbt, unsigned int want,
                                             int u, int pr0, unsigned int* stage) {
  if (u >= 43) return;
  uintx4 v[8];
  const unsigned int* addr[8];
#pragma unroll
  for (int i = 0; i < 8; ++i) addr[i] = mbt + (((pr0 + 4 * i) << 6) + u) * 4;
  unsigned int done = 0;
  int guard = 0;
  while (done != 0xffu && ++guard < (1 << 15)) {
#pragma unroll
    for (int i = 0; i < 8; ++i) {
      if (!(done & (1u << i))) {
        asm volatile("global_load_dwordx4 %0, %1, off sc0 sc1" : "=v"(v[i]) : "v"(addr[i]));
      }
    }
    asm volatile("s_waitcnt vmcnt(0)" ::: "memory");
#pragma unroll
    for (int i = 0; i < 8; ++i) {
      if (!(done & (1u << i))) {
        if (v[i][3] == want) {
          unsigned int* d = stage + (pr0 + 4 * i) * 128 + u * 3;
          d[0] = v[i][0];
          d[1] = v[i][1];
          if (u < 42) d[2] = v[i][2];
          done |= 1u << i;
        }
      }
    }
  }
}

// merged dual-mailbox volley: 8 units from A + 8 units from B in flight together
__device__ __forceinline__ void poll_scatter2(const unsigned int* mbtA, unsigned int wantA,
                                              const unsigned int* mbtB, unsigned int wantB,
                                              int u, int pr0,
                                              unsigned int* stA, unsigned int* stB) {
  if (u >= 43) return;
  uintx4 v[16];
  const unsigned int* addr[16];
#pragma unroll
  for (int i = 0; i < 8; ++i) {
    addr[i] = mbtA + (((pr0 + 4 * i) << 6) + u) * 4;
    addr[8 + i] = mbtB ? (mbtB + (((pr0 + 4 * i) << 6) + u) * 4) : nullptr;
  }
  unsigned int done = mbtB ? 0u : 0xff00u;
  int guard = 0;
  while (done != 0xffffu && ++guard < (1 << 15)) {
#pragma unroll
    for (int i = 0; i < 16; ++i) {
      if (!(done & (1u << i))) {
        asm volatile("global_load_dwordx4 %0, %1, off sc0 sc1" : "=v"(v[i]) : "v"(addr[i]));
      }
    }
    asm volatile("s_waitcnt vmcnt(0)" ::: "memory");
#pragma unroll
    for (int i = 0; i < 16; ++i) {
      if (!(done & (1u << i))) {
        unsigned int want = (i < 8) ? wantA : wantB;
        if (v[i][3] == want) {
          unsigned int* st = (i < 8) ? stA : stB;
          int q = (i < 8) ? i : (i - 8);
          unsigned int* d = st + (pr0 + 4 * q) * 128 + u * 3;
          d[0] = v[i][0];
          d[1] = v[i][1];
          if (u < 42) d[2] = v[i][2];
          done |= 1u << i;
        }
      }
    }
  }
}

__global__ __launch_bounds__(256, 1) void lstm_seq(
    const unsigned short* __restrict__ g0pre,  // [T][16][2048] bf16 (x@Wih0 + b0)
    const unsigned short* __restrict__ Whh0T,  // [2048][512] bf16
    const unsigned short* __restrict__ W1T,    // [2048][1024] bf16 (Wih1T | Whh1T)
    const float* __restrict__ b1,
    unsigned int* __restrict__ mb0,            // [257][32][64][4] u32 mailboxes
    unsigned int* __restrict__ mb1,
    unsigned short* __restrict__ out_a,        // [16][T][512] bf16
    unsigned short* __restrict__ cat) {        // [4096][1024] bf16 (right half filled here)
  __shared__ unsigned short wlds[32 * 1024];  // 64KB: L0=Whh0 slice; L1=Whh1 slice
  __shared__ float gx[4][16][17];
  __shared__ unsigned int hstage0[32 * 128];  // 16KB staged h (layer input A)
  __shared__ unsigned int hstage1[32 * 128];  // 16KB (L1's own-layer h)
  __shared__ unsigned int hpk[130];

  const int tid = threadIdx.x;
  const int wave = tid >> 6, lane = tid & 63;
  const int lrow = lane & 15, lkg = lane >> 4;
  const bool l1 = (blockIdx.x >= 32);
  const int cb = l1 ? ((int)blockIdx.x - 32) : (int)blockIdx.x;

  // stage weight slice into LDS (16B-chunk XOR swizzle), K=512 for both roles
  {
    const unsigned short* base = l1 ? W1T : Whh0T;
    const long rstride = l1 ? 1024 : 512;
    const long coff = l1 ? 512 : 0;
    for (int idx = tid; idx < 64 * 64; idx += 256) {
      int r = idx >> 6, c = idx & 63;
      int g = r >> 4, n = r & 15;
      const unsigned short* src = base + (long)(g * 512 + cb * 16 + n) * rstride + coff + c * 8;
      int cs = c ^ (n & 7);
      *(uint4*)((char*)wlds + (long)r * 1024 + cs * 16) = *(const uint4*)src;
    }
  }
  __syncthreads();

  const int b_ = tid >> 4, hc = tid & 15;
  const int u_ = tid & 63, pr0 = tid >> 6;
  float cst = 0.f;
  const float bv1 = l1 ? b1[wave * 512 + cb * 16 + lrow] : 0.f;
  const unsigned short* wrow1 = W1T + (long)(wave * 512 + cb * 16 + lrow) * 1024;  // Wih1 half

  for (int t = 0; t < TSEQ; ++t) {
    // gate-precompute prefetch (in flight during poll)
    floatx4 pre;
    if (!l1) {
      const unsigned short* gp = g0pre + (long)t * (16 * 2048) + wave * 512 + cb * 16 + lrow;
      pre[0] = bf2f(gp[(lkg * 4 + 0) * 2048]);
      pre[1] = bf2f(gp[(lkg * 4 + 1) * 2048]);
      pre[2] = bf2f(gp[(lkg * 4 + 2) * 2048]);
      pre[3] = bf2f(gp[(lkg * 4 + 3) * 2048]);
    } else {
      pre = floatx4{bv1, bv1, bv1, bv1};
    }

    floatx4 acc0 = pre, acc1 = floatx4{0.f, 0.f, 0.f, 0.f};

    if (!l1) {
      if (t > 0) {
        poll_scatter(mb0 + (long)t * 8192, (unsigned)t, u_, pr0, hstage0);
        __syncthreads();
#pragma unroll 8
        for (int ks = 0; ks < 16; ++ks) {
          int c32 = ks * 16 + lkg * 4;
          uint4 uu = *(const uint4*)(hstage0 + ((c32 >> 3) * 128 + lrow * 8 + (c32 & 7)));
          bf16x8 af = __builtin_bit_cast(bf16x8, uu);
          int ch = (ks * 4 + lkg) ^ (lrow & 7);
          bf16x8 bfv = *(const bf16x8*)((const char*)wlds + (long)(wave * 16 + lrow) * 1024 + ch * 16);
          if (ks & 1)
            acc1 = __builtin_amdgcn_mfma_f32_16x16x32_bf16(af, bfv, acc1, 0, 0, 0);
          else
            acc0 = __builtin_amdgcn_mfma_f32_16x16x32_bf16(af, bfv, acc0, 0, 0, 0);
        }
      }
    } else {
      // merged volley: h0[t+1] (input half) + h1[t] (recurrent half) concurrently
      poll_scatter2(mb0 + (long)(t + 1) * 8192, (unsigned)(t + 1),
                    (t > 0) ? (mb1 + (long)t * 8192) : nullptr, (unsigned)t,
                    u_, pr0, hstage0, hstage1);
      __syncthreads();
#pragma unroll 8
      for (int ks = 0; ks < 16; ++ks) {
        int c32 = ks * 16 + lkg * 4;
        uint4 uu = *(const uint4*)(hstage0 + ((c32 >> 3) * 128 + lrow * 8 + (c32 & 7)));
        bf16x8 af = __builtin_bit_cast(bf16x8, uu);
        bf16x8 bfv = *(const bf16x8*)(wrow1 + ks * 32 + lkg * 8);
        if (ks & 1)
          acc1 = __builtin_amdgcn_mfma_f32_16x16x32_bf16(af, bfv, acc1, 0, 0, 0);
        else
          acc0 = __builtin_amdgcn_mfma_f32_16x16x32_bf16(af, bfv, acc0, 0, 0, 0);
      }
      if (t > 0) {
#pragma unroll 8
        for (int ks = 0; ks < 16; ++ks) {
          int c32 = ks * 16 + lkg * 4;
          uint4 uu = *(const uint4*)(hstage1 + ((c32 >> 3) * 128 + lrow * 8 + (c32 & 7)));
          bf16x8 af = __builtin_bit_cast(bf16x8, uu);
          int ch = (ks * 4 + lkg) ^ (lrow & 7);
          bf16x8 bfv = *(const bf16x8*)((const char*)wlds + (long)(wave * 16 + lrow) * 1024 + ch * 16);
          if (ks & 1)
            acc1 = __builtin_amdgcn_mfma_f32_16x16x32_bf16(af, bfv, acc1, 0, 0, 0);
          else
            acc0 = __builtin_amdgcn_mfma_f32_16x16x32_bf16(af, bfv, acc0, 0, 0, 0);
        }
      }
    }
    acc0 += acc1;

    gx[wave][lkg * 4 + 0][lrow] = acc0[0];
    gx[wave][lkg * 4 + 1][lrow] = acc0[1];
    gx[wave][lkg * 4 + 2][lrow] = acc0[2];
    gx[wave][lkg * 4 + 3][lrow] = acc0[3];
    __syncthreads();

    float gi = gx[0][b_][hc], gf = gx[1][b_][hc], gg = gx[2][b_][hc], go = gx[3][b_][hc];
    float ct = sigmoidf_(gf) * cst + sigmoidf_(gi) * tanhf_(gg);
    cst = ct;
    float hv = sigmoidf_(go) * tanhf_(ct);
    unsigned int hb = f2bf(hv);
    unsigned int nb = (unsigned int)__shfl_xor((int)hb, 1);
    if ((hc & 1) == 0) hpk[b_ * 8 + (hc >> 1)] = hb | (nb << 16);
    if (l1) {
      out_a[(long)b_ * (TSEQ * 512) + (long)t * 512 + cb * 16 + hc] = (unsigned short)hb;
      cat[(long)(b_ * 256 + t) * 1024 + 512 + cb * 16 + hc] = (unsigned short)hb;
    }
    __syncthreads();

    // publish: 43 single-lane 16B stores, epoch embedded. fire-and-forget.
    if (tid < 43) {
      uintx4 pkt;
      pkt[0] = hpk[3 * tid];
      pkt[1] = hpk[3 * tid + 1];
      pkt[2] = (tid < 42) ? hpk[3 * tid + 2] : 0u;
      pkt[3] = (unsigned int)(t + 1);
      unsigned int* dst = (l1 ? mb1 : mb0) + (long)(t + 1) * 8192 + ((cb << 6) + tid) * 4;
      asm volatile("global_store_dwordx4 %0, %1, off sc0 sc1" :: "v"(dst), "v"(pkt) : "memory");
    }
  }
}

// ---------------- masked column-softmax (scores symmetric) -> wT[b][j][i] bf16 ----------------
__global__ __launch_bounds__(256) void softmax_w(
    const float* __restrict__ scores, const int* __restrict__ tok, unsigned short* __restrict__ wT) {
  int wave = threadIdx.x >> 6, lane = threadIdx.x & 63;
  int rowid = blockIdx.x * 4 + wave;  // b*256 + j
  int b = rowid >> 8;
  const float* srow = scores + (long)rowid * 256;
  int i0 = lane * 4;
  float4 s = *(const float4*)(srow + i0);
  const int* tg = tok + b * 257 + 1 + i0;
  bool m0 = tg[0] != 0, m1 = tg[1] != 0, m2 = tg[2] != 0, m3 = tg[3] != 0;
  float v0 = m0 ? s.x : -1e30f, v1 = m1 ? s.y : -1e30f;
  float v2 = m2 ? s.z : -1e30f, v3 = m3 ? s.w : -1e30f;
  float mx = fmaxf(fmaxf(v0, v1), fmaxf(v2, v3));
#pragma unroll
  for (int off = 32; off; off >>= 1) mx = fmaxf(mx, __shfl_xor(mx, off));
  float p0 = m0 ? __expf(s.x - mx) : 0.f;
  float p1 = m1 ? __expf(s.y - mx) : 0.f;
  float p2 = m2 ? __expf(s.z - mx) : 0.f;
  float p3 = m3 ? __expf(s.w - mx) : 0.f;
  float sum = p0 + p1 + p2 + p3;
#pragma unroll
  for (int off = 32; off; off >>= 1) sum += __shfl_xor(sum, off);
  float inv = sum > 0.f ? 1.f / sum : 0.f;
  unsigned short* o = wT + (long)rowid * 256 + i0;
  o[0] = f2bf(p0 * inv);
  o[1] = f2bf(p1 * inv);
  o[2] = f2bf(p2 * inv);
  o[3] = f2bf(p3 * inv);
}

extern "C" void kernel_launch(void* const* d_in, const int* in_sizes, int n_in,
                              void* d_out, int out_size, void* d_ws, size_t ws_size,
                              hipStream_t stream) {
  const int* tok = (const int*)d_in[0];
  const float* emb = (const float*)d_in[1];
  const float* Wih0 = (const float*)d_in[2];
  const float* Whh0 = (const float*)d_in[3];
  const float* b0 = (const float*)d_in[4];
  const float* Wih1 = (const float*)d_in[5];
  const float* Whh1 = (const float*)d_in[6];
  const float* b1 = (const float*)d_in[7];
  const float* Wc = (const float*)d_in[8];
  const float* bc = (const float*)d_in[9];
  const float* Wp = (const float*)d_in[10];
  const float* bp = (const float*)d_in[11];

  char* ws = (char*)d_ws;
  size_t off = 0;
  auto alloc = [&](size_t bytes) {
    char* p = ws + off;
    off += (bytes + 255) & ~(size_t)255;
    return p;
  };

  unsigned short* WpT = (unsigned short*)alloc((size_t)VV * 512 * 2);
  unsigned short* WcT = (unsigned short*)alloc((size_t)512 * 1024 * 2);
  unsigned short* Wih0T = (unsigned short*)alloc((size_t)2048 * 512 * 2);
  unsigned short* Whh0T = (unsigned short*)alloc((size_t)2048 * 512 * 2);
  unsigned short* W1T = (unsigned short*)alloc((size_t)2048 * 1024 * 2);
  unsigned short* xbf = (unsigned short*)alloc((size_t)4096 * 512 * 2);
  unsigned short* g0pre = (unsigned short*)alloc((size_t)4096 * 2048 * 2);
  unsigned int* mb0 = (unsigned int*)alloc((size_t)257 * 8192 * 4);
  unsigned int* mb1 = (unsigned int*)alloc((size_t)257 * 8192 * 4);
  unsigned short* out_a = (unsigned short*)alloc((size_t)16 * 256 * 512 * 2);
  unsigned short* outT = (unsigned short*)alloc((size_t)16 * 512 * 256 * 2);
  float* scores = (float*)alloc((size_t)16 * 256 * 256 * 4);
  unsigned short* wT = (unsigned short*)alloc((size_t)16 * 256 * 256 * 2);
  unsigned short* cat = (unsigned short*)alloc((size_t)4096 * 1024 * 2);
  unsigned short* pred = (unsigned short*)alloc((size_t)4096 * 512 * 2);

  // mailbox epoch reset (replay safety): must precede lstm_seq on this stream
  (void)hipMemsetAsync(mb0, 0, (size_t)257 * 8192 * 4, stream);
  (void)hipMemsetAsync(mb1, 0, (size_t)257 * 8192 * 4, stream);

  // fused weight transposes (fp32 -> bf16, (K,N) -> (N,K)): 6 jobs, one dispatch
  transpose_all<<<20608, 256, 0, stream>>>(Wp, WpT, Wc, WcT, Wih0, Wih0T, Whh0, Whh0T,
                                           Wih1, Whh1, W1T);

  embed_gather<<<4096, 128, 0, stream>>>(tok, emb, xbf);

  // G1: g0pre = x @ Wih0 + b0   (rows t*16+b, bf16 out)
  gemm_bt<1, 1, 0><<<dim3(2048 / 128, 4096 / 128, 1), 256, 0, stream>>>(
      xbf, Wih0T, g0pre, b0, 512, 2048, 0, 0, 0);

  lstm_seq<<<64, 256, 0, stream>>>(g0pre, Whh0T, W1T, b1, mb0, mb1, out_a, cat);

  // outT[b][h][t]
  transpose_bf16<unsigned short><<<dim3(512 / 32, 256 / 32, 16), 256, 0, stream>>>(
      out_a, outT, 256, 512, 256, (long)256 * 512, (long)512 * 256);

  // scores[b][i][j] = out_i . out_j  (fp32)
  gemm_bt<0, 0, 0><<<dim3(2, 2, 16), 256, 0, stream>>>(
      out_a, out_a, scores, nullptr, 512, 256, (long)256 * 512, (long)256 * 512, (long)256 * 256);

  softmax_w<<<1024, 256, 0, stream>>>(scores, tok, wT);

  // ctx[b][j][h] -> cat[:, :512] (bf16)
  gemm_bt<1, 0, 0><<<dim3(4, 2, 16), 256, 0, stream>>>(
      wT, outT, cat, nullptr, 256, 1024, (long)256 * 256, (long)512 * 256, (long)256 * 1024);

  // pred = tanh(cat @ Wc + bc) (bf16)
  gemm_bt<1, 1, 1><<<dim3(512 / 128, 4096 / 128, 1), 256, 0, stream>>>(
      cat, WcT, pred, bc, 1024, 512, 0, 0, 0);

  // logits = pred @ Wp + bp -> d_out (fp32)
  gemm_bt<0, 1, 0><<<dim3(VV / 128, 4096 / 128, 1), 256, 0, stream>>>(
      pred, WpT, d_out, bp, 512, VV, 0, 0, 0);
}

// Round 15
// 1591.333 us; speedup vs baseline: 1.0362x; 1.0362x over previous
//
#include <hip/hip_runtime.h>
#include <hip/hip_bf16.h>

#define TSEQ 256
#define NB 16
#define DD 512
#define HHH 512
#define VV 32000

typedef __attribute__((ext_vector_type(4))) float floatx4;
typedef __attribute__((ext_vector_type(8))) __bf16 bf16x8;
typedef __attribute__((ext_vector_type(4))) unsigned int uintx4;

__device__ __forceinline__ float sigmoidf_(float x) { return 1.f / (1.f + __expf(-x)); }
__device__ __forceinline__ float tanhf_(float x) {
  float e = __expf(2.f * x);
  return (e - 1.f) / (e + 1.f);
}

__device__ __forceinline__ unsigned short f2bf(float f) {
  __hip_bfloat16 h = __float2bfloat16(f);
  return __builtin_bit_cast(unsigned short, h);
}
__device__ __forceinline__ float bf2f(unsigned short u) {
  unsigned int v = ((unsigned int)u) << 16;
  return __builtin_bit_cast(float, v);
}

__device__ __forceinline__ void gld_lds16(const void* g, void* l) {
  __builtin_amdgcn_global_load_lds((const __attribute__((address_space(1))) void*)g,
                                   (__attribute__((address_space(3))) void*)l, 16, 0, 0);
}

// ---------------- Generic bf16 MFMA GEMM: C = A(MxK) * Bt(NxK)^T (+bias)(+tanh) ----------------
// SWZ: bijective XCD-chunk remap of the (x,y) grid for L2 locality (z must be 1).
// f32 output path uses an LDS-bounce epilogue: 16x64 wave tile staged in LDS,
// read back row-major, stored as dwordx4 (256B/row coalescing on the C-write).
template <int OUT_BF16, int HAS_BIAS, int ACT_TANH, int SWZ>
__global__ __launch_bounds__(256, 2) void gemm_bt(
    const unsigned short* __restrict__ A, const unsigned short* __restrict__ Bt,
    void* __restrict__ Cv, const float* __restrict__ bias,
    int K, int ldc, long sA, long sB, long sC) {
  __shared__ unsigned short As[128 * 32];
  __shared__ unsigned short Bs[128 * 32];
  __shared__ float cstage[4][16][65];
  const int tid = threadIdx.x;
  const int wave = tid >> 6, lane = tid & 63;
  const int lrow = lane & 15, lkg = lane >> 4;
  const int wr = wave >> 1, wc = wave & 1;
  const int bz = blockIdx.z;

  int bx_ = blockIdx.x, by_ = blockIdx.y;
  if (SWZ) {
    int gx = gridDim.x;
    int nwg = gx * gridDim.y;
    int lin = by_ * gx + bx_;
    int q = nwg >> 3, r = nwg & 7;
    int xcd = lin & 7, pos = lin >> 3;
    int nl = (xcd < r ? xcd * (q + 1) : r * (q + 1) + (xcd - r) * q) + pos;
    bx_ = nl % gx;
    by_ = nl / gx;
  }

  const unsigned short* Ab = A + (long)bz * sA + (long)by_ * 128 * K;
  const unsigned short* Bb = Bt + (long)bz * sB + (long)bx_ * 128 * K;

  const int srow = tid >> 2;
  const int scg = (tid & 3) ^ ((tid >> 3) & 3);
  const long srcOff = (long)srow * K + scg * 8;

  char* aDst = (char*)As + wave * 1024;
  char* bDst = (char*)Bs + wave * 1024;

  floatx4 acc[4][4];
#pragma unroll
  for (int i = 0; i < 4; ++i)
#pragma unroll
    for (int j = 0; j < 4; ++j) acc[i][j] = floatx4{0.f, 0.f, 0.f, 0.f};

  for (int k0 = 0; k0 < K; k0 += 32) {
    gld_lds16(Ab + srcOff + k0, aDst);
    gld_lds16(Ab + srcOff + (long)64 * K + k0, aDst + 4096);
    gld_lds16(Bb + srcOff + k0, bDst);
    gld_lds16(Bb + srcOff + (long)64 * K + k0, bDst + 4096);
    __syncthreads();
    bf16x8 af[4], bfr[4];
#pragma unroll
    for (int mi = 0; mi < 4; ++mi) {
      int R = wr * 64 + mi * 16 + lrow;
      int cg = lkg ^ ((R >> 1) & 3);
      af[mi] = *(const bf16x8*)((const char*)As + R * 64 + cg * 16);
    }
#pragma unroll
    for (int ni = 0; ni < 4; ++ni) {
      int R = wc * 64 + ni * 16 + lrow;
      int cg = lkg ^ ((R >> 1) & 3);
      bfr[ni] = *(const bf16x8*)((const char*)Bs + R * 64 + cg * 16);
    }
#pragma unroll
    for (int mi = 0; mi < 4; ++mi)
#pragma unroll
      for (int ni = 0; ni < 4; ++ni)
        acc[mi][ni] = __builtin_amdgcn_mfma_f32_16x16x32_bf16(af[mi], bfr[ni], acc[mi][ni], 0, 0, 0);
    __syncthreads();
  }

  const int mBase = by_ * 128 + wr * 64 + lkg * 4;
  const int nBase = bx_ * 128 + wc * 64 + lrow;

  if (!OUT_BF16) {
    // LDS-bounce coalesced epilogue (f32)
    float* Cf = (float*)Cv + (long)bz * sC;
#pragma unroll
    for (int mi = 0; mi < 4; ++mi) {
#pragma unroll
      for (int ni = 0; ni < 4; ++ni) {
        float bv = HAS_BIAS ? bias[bx_ * 128 + wc * 64 + ni * 16 + lrow] : 0.f;
#pragma unroll
        for (int r = 0; r < 4; ++r) {
          float v = acc[mi][ni][r] + bv;
          if (ACT_TANH) v = tanhf(v);
          cstage[wave][lkg * 4 + r][ni * 16 + lrow] = v;
        }
      }
      __builtin_amdgcn_s_waitcnt(0);  // lgkmcnt(0): wave-local LDS ordering
#pragma unroll
      for (int p = 0; p < 4; ++p) {
        int rr = p * 4 + (lane >> 4);
        int cc = (lane & 15) * 4;
        float4 ov = *(const float4*)&cstage[wave][rr][cc];
        long row = (long)(by_ * 128 + wr * 64 + mi * 16 + rr);
        long col = (long)(bx_ * 128 + wc * 64 + cc);
        *(float4*)(Cf + row * ldc + col) = ov;
      }
      __builtin_amdgcn_s_waitcnt(0);
    }
  } else {
#pragma unroll
    for (int ni = 0; ni < 4; ++ni) {
      int n = nBase + ni * 16;
      float bv = HAS_BIAS ? bias[n] : 0.f;
#pragma unroll
      for (int mi = 0; mi < 4; ++mi) {
        int m = mBase + mi * 16;
#pragma unroll
        for (int r = 0; r < 4; ++r) {
          float v = acc[mi][ni][r] + bv;
          if (ACT_TANH) v = tanhf(v);
          ((unsigned short*)Cv)[(long)bz * sC + (long)(m + r) * ldc + n] = f2bf(v);
        }
      }
    }
  }
}

// ---------------- transpose + convert to bf16: out[n][k] = in[k][n] ----------------
__device__ __forceinline__ float ldval(const float* p) { return *p; }
__device__ __forceinline__ float ldval(const unsigned short* p) { return bf2f(*p); }

template <typename TIN>
__global__ __launch_bounds__(256) void transpose_bf16(
    const TIN* __restrict__ in, unsigned short* __restrict__ out,
    int Kdim, int Ndim, int ldout, long sIn, long sOut) {
  __shared__ float tile[32][33];
  const int bz = blockIdx.z;
  in += (long)bz * sIn;
  out += (long)bz * sOut;
  int n0 = blockIdx.x * 32, k0 = blockIdx.y * 32;
  int tx = threadIdx.x & 31, ty = threadIdx.x >> 5;
#pragma unroll
  for (int j = 0; j < 4; ++j) {
    int k = k0 + ty + j * 8;
    tile[ty + j * 8][tx] = ldval(in + (long)k * Ndim + n0 + tx);
  }
  __syncthreads();
#pragma unroll
  for (int j = 0; j < 4; ++j) {
    int n = n0 + ty + j * 8;
    out[(long)n * ldout + k0 + tx] = f2bf(tile[tx][ty + j * 8]);
  }
}

// ---------------- fused weight transposes (6 jobs in one dispatch) ----------------
__global__ __launch_bounds__(256) void transpose_all(
    const float* __restrict__ Wp, unsigned short* __restrict__ WpT,
    const float* __restrict__ Wc, unsigned short* __restrict__ WcT,
    const float* __restrict__ Wih0, unsigned short* __restrict__ Wih0T,
    const float* __restrict__ Whh0, unsigned short* __restrict__ Whh0T,
    const float* __restrict__ Wih1, const float* __restrict__ Whh1,
    unsigned short* __restrict__ W1T) {
  __shared__ float tile[32][33];
  int id = blockIdx.x;
  const float* in;
  unsigned short* out;
  int Ndim, ldout, bx, by;
  if (id < 16000) {            // Wp (512 x 32000) -> WpT (32000 x 512)
    in = Wp; out = WpT; Ndim = VV; ldout = 512;
    bx = id % 1000; by = id / 1000;
  } else if (id < 16512) {     // Wc (1024 x 512) -> WcT (512 x 1024)
    id -= 16000;
    in = Wc; out = WcT; Ndim = 512; ldout = 1024;
    bx = id % 16; by = id / 16;
  } else if (id < 17536) {     // Wih0 (512 x 2048) -> Wih0T (2048 x 512)
    id -= 16512;
    in = Wih0; out = Wih0T; Ndim = 2048; ldout = 512;
    bx = id % 64; by = id / 64;
  } else if (id < 18560) {     // Whh0 -> Whh0T
    id -= 17536;
    in = Whh0; out = Whh0T; Ndim = 2048; ldout = 512;
    bx = id % 64; by = id / 64;
  } else if (id < 19584) {     // Wih1 -> W1T[:, 0:512]
    id -= 18560;
    in = Wih1; out = W1T; Ndim = 2048; ldout = 1024;
    bx = id % 64; by = id / 64;
  } else {                     // Whh1 -> W1T[:, 512:1024]
    id -= 19584;
    in = Whh1; out = W1T + 512; Ndim = 2048; ldout = 1024;
    bx = id % 64; by = id / 64;
  }
  int n0 = bx * 32, k0 = by * 32;
  int tx = threadIdx.x & 31, ty = threadIdx.x >> 5;
#pragma unroll
  for (int j = 0; j < 4; ++j) {
    int k = k0 + ty + j * 8;
    tile[ty + j * 8][tx] = in[(long)k * Ndim + n0 + tx];
  }
  __syncthreads();
#pragma unroll
  for (int j = 0; j < 4; ++j) {
    int n = n0 + ty + j * 8;
    out[(long)n * ldout + k0 + tx] = f2bf(tile[tx][ty + j * 8]);
  }
}

// ---------------- embedding gather -> bf16, rows (t*16+b) ----------------
__global__ __launch_bounds__(128) void embed_gather(
    const int* __restrict__ tok, const float* __restrict__ emb, unsigned short* __restrict__ x) {
  int rid = blockIdx.x;  // t*16 + b
  int t = rid >> 4, b = rid & 15;
  int tokv = tok[b * 257 + t];
  const float* er = emb + (long)tokv * DD;
  int d = threadIdx.x * 4;
  float4 v = *(const float4*)(er + d);
  unsigned short* xp = x + (long)rid * DD + d;
  xp[0] = f2bf(v.x);
  xp[1] = f2bf(v.y);
  xp[2] = f2bf(v.z);
  xp[3] = f2bf(v.w);
}

// ================= EPOCH-EMBEDDED MAILBOX LSTM (R13 structure, proven 1270us) =================
// Mailbox per layer: mb[t][producer 0..31][unit 0..63] x 16B.
// A unit = {3 data dwords (packed bf16 pairs), epoch dword = t}. Producer's h-slice
// (16 batches x 8 packed u32 = 128 dwords) occupies units 0..42. Producer: single-lane
// dwordx4 sc0 sc1 stores, fire-and-forget (epoch rides in the SAME 16B store as its
// data -> no vmcnt/flag/barrier). Consumer: parallel dwordx4 sc0 sc1 poll-loads;
// accept unit when [3]==epoch (detection IS the fetch -- single MALL round).
// Mailboxes zeroed each launch (replay safety). Polls bounded (never hangs).

__device__ __forceinline__ void poll_scatter(const unsigned int* mbt, unsigned int want,
                                             int u, int pr0, unsigned int* stage) {
  if (u >= 43) return;
  uintx4 v[8];
  const unsigned int* addr[8];
#pragma unroll
  for (int i = 0; i < 8; ++i) addr[i] = mbt + (((pr0 + 4 * i) << 6) + u) * 4;
  unsigned int done = 0;
  int guard = 0;
  while (done != 0xffu && ++guard < (1 << 15)) {
#pragma unroll
    for (int i = 0; i < 8; ++i) {
      if (!(done & (1u << i))) {
        asm volatile("global_load_dwordx4 %0, %1, off sc0 sc1" : "=v"(v[i]) : "v"(addr[i]));
      }
    }
    asm volatile("s_waitcnt vmcnt(0)" ::: "memory");
#pragma unroll
    for (int i = 0; i < 8; ++i) {
      if (!(done & (1u << i))) {
        if (v[i][3] == want) {
          unsigned int* d = stage + (pr0 + 4 * i) * 128 + u * 3;
          d[0] = v[i][0];
          d[1] = v[i][1];
          if (u < 42) d[2] = v[i][2];
          done |= 1u << i;
        }
      }
    }
  }
}

__global__ __launch_bounds__(256, 1) void lstm_seq(
    const unsigned short* __restrict__ g0pre,  // [T][16][2048] bf16 (x@Wih0 + b0)
    const unsigned short* __restrict__ Whh0T,  // [2048][512] bf16
    const unsigned short* __restrict__ W1T,    // [2048][1024] bf16 (Wih1T | Whh1T)
    const float* __restrict__ b1,
    unsigned int* __restrict__ mb0,            // [257][32][64][4] u32 mailboxes
    unsigned int* __restrict__ mb1,
    unsigned short* __restrict__ out_a,        // [16][T][512] bf16
    unsigned short* __restrict__ cat) {        // [4096][1024] bf16 (right half filled here)
  __shared__ unsigned short wlds[32 * 1024];  // 64KB: L0=Whh0 slice; L1=Whh1 slice
  __shared__ float gx[4][16][17];
  __shared__ unsigned int hstage0[32 * 128];  // 16KB staged h (layer input A)
  __shared__ unsigned int hstage1[32 * 128];  // 16KB (L1's own-layer h)
  __shared__ unsigned int hpk[130];

  const int tid = threadIdx.x;
  const int wave = tid >> 6, lane = tid & 63;
  const int lrow = lane & 15, lkg = lane >> 4;
  const bool l1 = (blockIdx.x >= 32);
  const int cb = l1 ? ((int)blockIdx.x - 32) : (int)blockIdx.x;

  // stage weight slice into LDS (16B-chunk XOR swizzle), K=512 for both roles
  {
    const unsigned short* base = l1 ? W1T : Whh0T;
    const long rstride = l1 ? 1024 : 512;
    const long coff = l1 ? 512 : 0;
    for (int idx = tid; idx < 64 * 64; idx += 256) {
      int r = idx >> 6, c = idx & 63;
      int g = r >> 4, n = r & 15;
      const unsigned short* src = base + (long)(g * 512 + cb * 16 + n) * rstride + coff + c * 8;
      int cs = c ^ (n & 7);
      *(uint4*)((char*)wlds + (long)r * 1024 + cs * 16) = *(const uint4*)src;
    }
  }
  __syncthreads();

  const int b_ = tid >> 4, hc = tid & 15;
  const int u_ = tid & 63, pr0 = tid >> 6;
  float cst = 0.f;
  const float bv1 = l1 ? b1[wave * 512 + cb * 16 + lrow] : 0.f;
  const unsigned short* wrow1 = W1T + (long)(wave * 512 + cb * 16 + lrow) * 1024;  // Wih1 half

  for (int t = 0; t < TSEQ; ++t) {
    // gate-precompute prefetch (in flight during poll)
    floatx4 pre;
    if (!l1) {
      const unsigned short* gp = g0pre + (long)t * (16 * 2048) + wave * 512 + cb * 16 + lrow;
      pre[0] = bf2f(gp[(lkg * 4 + 0) * 2048]);
      pre[1] = bf2f(gp[(lkg * 4 + 1) * 2048]);
      pre[2] = bf2f(gp[(lkg * 4 + 2) * 2048]);
      pre[3] = bf2f(gp[(lkg * 4 + 3) * 2048]);
    } else {
      pre = floatx4{bv1, bv1, bv1, bv1};
    }

    floatx4 acc0 = pre, acc1 = floatx4{0.f, 0.f, 0.f, 0.f};

    if (!l1) {
      if (t > 0) {
        poll_scatter(mb0 + (long)t * 8192, (unsigned)t, u_, pr0, hstage0);
        __syncthreads();
#pragma unroll 8
        for (int ks = 0; ks < 16; ++ks) {
          int c32 = ks * 16 + lkg * 4;
          uint4 uu = *(const uint4*)(hstage0 + ((c32 >> 3) * 128 + lrow * 8 + (c32 & 7)));
          bf16x8 af = __builtin_bit_cast(bf16x8, uu);
          int ch = (ks * 4 + lkg) ^ (lrow & 7);
          bf16x8 bfv = *(const bf16x8*)((const char*)wlds + (long)(wave * 16 + lrow) * 1024 + ch * 16);
          if (ks & 1)
            acc1 = __builtin_amdgcn_mfma_f32_16x16x32_bf16(af, bfv, acc1, 0, 0, 0);
          else
            acc0 = __builtin_amdgcn_mfma_f32_16x16x32_bf16(af, bfv, acc0, 0, 0, 0);
        }
      }
    } else {
      // h0 input half (Wih1 streamed from cache)
      poll_scatter(mb0 + (long)(t + 1) * 8192, (unsigned)(t + 1), u_, pr0, hstage0);
      __syncthreads();
#pragma unroll 8
      for (int ks = 0; ks < 16; ++ks) {
        int c32 = ks * 16 + lkg * 4;
        uint4 uu = *(const uint4*)(hstage0 + ((c32 >> 3) * 128 + lrow * 8 + (c32 & 7)));
        bf16x8 af = __builtin_bit_cast(bf16x8, uu);
        bf16x8 bfv = *(const bf16x8*)(wrow1 + ks * 32 + lkg * 8);
        if (ks & 1)
          acc1 = __builtin_amdgcn_mfma_f32_16x16x32_bf16(af, bfv, acc1, 0, 0, 0);
        else
          acc0 = __builtin_amdgcn_mfma_f32_16x16x32_bf16(af, bfv, acc0, 0, 0, 0);
      }
      // own-layer recurrent half (Whh1 in LDS)
      if (t > 0) {
        poll_scatter(mb1 + (long)t * 8192, (unsigned)t, u_, pr0, hstage1);
        __syncthreads();
#pragma unroll 8
        for (int ks = 0; ks < 16; ++ks) {
          int c32 = ks * 16 + lkg * 4;
          uint4 uu = *(const uint4*)(hstage1 + ((c32 >> 3) * 128 + lrow * 8 + (c32 & 7)));
          bf16x8 af = __builtin_bit_cast(bf16x8, uu);
          int ch = (ks * 4 + lkg) ^ (lrow & 7);
          bf16x8 bfv = *(const bf16x8*)((const char*)wlds + (long)(wave * 16 + lrow) * 1024 + ch * 16);
          if (ks & 1)
            acc1 = __builtin_amdgcn_mfma_f32_16x16x32_bf16(af, bfv, acc1, 0, 0, 0);
          else
            acc0 = __builtin_amdgcn_mfma_f32_16x16x32_bf16(af, bfv, acc0, 0, 0, 0);
        }
      }
    }
    acc0 += acc1;

    gx[wave][lkg * 4 + 0][lrow] = acc0[0];
    gx[wave][lkg * 4 + 1][lrow] = acc0[1];
    gx[wave][lkg * 4 + 2][lrow] = acc0[2];
    gx[wave][lkg * 4 + 3][lrow] = acc0[3];
    __syncthreads();

    float gi = gx[0][b_][hc], gf = gx[1][b_][hc], gg = gx[2][b_][hc], go = gx[3][b_][hc];
    float ct = sigmoidf_(gf) * cst + sigmoidf_(gi) * tanhf_(gg);
    cst = ct;
    float hv = sigmoidf_(go) * tanhf_(ct);
    unsigned int hb = f2bf(hv);
    unsigned int nb = (unsigned int)__shfl_xor((int)hb, 1);
    if ((hc & 1) == 0) hpk[b_ * 8 + (hc >> 1)] = hb | (nb << 16);
    if (l1) {
      out_a[(long)b_ * (TSEQ * 512) + (long)t * 512 + cb * 16 + hc] = (unsigned short)hb;
      cat[(long)(b_ * 256 + t) * 1024 + 512 + cb * 16 + hc] = (unsigned short)hb;
    }
    __syncthreads();

    // publish: 43 single-lane 16B stores, epoch embedded. fire-and-forget.
    if (tid < 43) {
      uintx4 pkt;
      pkt[0] = hpk[3 * tid];
      pkt[1] = hpk[3 * tid + 1];
      pkt[2] = (tid < 42) ? hpk[3 * tid + 2] : 0u;
      pkt[3] = (unsigned int)(t + 1);
      unsigned int* dst = (l1 ? mb1 : mb0) + (long)(t + 1) * 8192 + ((cb << 6) + tid) * 4;
      asm volatile("global_store_dwordx4 %0, %1, off sc0 sc1" :: "v"(dst), "v"(pkt) : "memory");
    }
  }
}

// ---------------- masked column-softmax (scores symmetric) -> wT[b][j][i] bf16 ----------------
__global__ __launch_bounds__(256) void softmax_w(
    const float* __restrict__ scores, const int* __restrict__ tok, unsigned short* __restrict__ wT) {
  int wave = threadIdx.x >> 6, lane = threadIdx.x & 63;
  int rowid = blockIdx.x * 4 + wave;  // b*256 + j
  int b = rowid >> 8;
  const float* srow = scores + (long)rowid * 256;
  int i0 = lane * 4;
  float4 s = *(const float4*)(srow + i0);
  const int* tg = tok + b * 257 + 1 + i0;
  bool m0 = tg[0] != 0, m1 = tg[1] != 0, m2 = tg[2] != 0, m3 = tg[3] != 0;
  float v0 = m0 ? s.x : -1e30f, v1 = m1 ? s.y : -1e30f;
  float v2 = m2 ? s.z : -1e30f, v3 = m3 ? s.w : -1e30f;
  float mx = fmaxf(fmaxf(v0, v1), fmaxf(v2, v3));
#pragma unroll
  for (int off = 32; off; off >>= 1) mx = fmaxf(mx, __shfl_xor(mx, off));
  float p0 = m0 ? __expf(s.x - mx) : 0.f;
  float p1 = m1 ? __expf(s.y - mx) : 0.f;
  float p2 = m2 ? __expf(s.z - mx) : 0.f;
  float p3 = m3 ? __expf(s.w - mx) : 0.f;
  float sum = p0 + p1 + p2 + p3;
#pragma unroll
  for (int off = 32; off; off >>= 1) sum += __shfl_xor(sum, off);
  float inv = sum > 0.f ? 1.f / sum : 0.f;
  unsigned short* o = wT + (long)rowid * 256 + i0;
  o[0] = f2bf(p0 * inv);
  o[1] = f2bf(p1 * inv);
  o[2] = f2bf(p2 * inv);
  o[3] = f2bf(p3 * inv);
}

extern "C" void kernel_launch(void* const* d_in, const int* in_sizes, int n_in,
                              void* d_out, int out_size, void* d_ws, size_t ws_size,
                              hipStream_t stream) {
  const int* tok = (const int*)d_in[0];
  const float* emb = (const float*)d_in[1];
  const float* Wih0 = (const float*)d_in[2];
  const float* Whh0 = (const float*)d_in[3];
  const float* b0 = (const float*)d_in[4];
  const float* Wih1 = (const float*)d_in[5];
  const float* Whh1 = (const float*)d_in[6];
  const float* b1 = (const float*)d_in[7];
  const float* Wc = (const float*)d_in[8];
  const float* bc = (const float*)d_in[9];
  const float* Wp = (const float*)d_in[10];
  const float* bp = (const float*)d_in[11];

  char* ws = (char*)d_ws;
  size_t off = 0;
  auto alloc = [&](size_t bytes) {
    char* p = ws + off;
    off += (bytes + 255) & ~(size_t)255;
    return p;
  };

  unsigned short* WpT = (unsigned short*)alloc((size_t)VV * 512 * 2);
  unsigned short* WcT = (unsigned short*)alloc((size_t)512 * 1024 * 2);
  unsigned short* Wih0T = (unsigned short*)alloc((size_t)2048 * 512 * 2);
  unsigned short* Whh0T = (unsigned short*)alloc((size_t)2048 * 512 * 2);
  unsigned short* W1T = (unsigned short*)alloc((size_t)2048 * 1024 * 2);
  unsigned short* xbf = (unsigned short*)alloc((size_t)4096 * 512 * 2);
  unsigned short* g0pre = (unsigned short*)alloc((size_t)4096 * 2048 * 2);
  unsigned int* mb0 = (unsigned int*)alloc((size_t)257 * 8192 * 4);
  unsigned int* mb1 = (unsigned int*)alloc((size_t)257 * 8192 * 4);
  unsigned short* out_a = (unsigned short*)alloc((size_t)16 * 256 * 512 * 2);
  unsigned short* outT = (unsigned short*)alloc((size_t)16 * 512 * 256 * 2);
  float* scores = (float*)alloc((size_t)16 * 256 * 256 * 4);
  unsigned short* wT = (unsigned short*)alloc((size_t)16 * 256 * 256 * 2);
  unsigned short* cat = (unsigned short*)alloc((size_t)4096 * 1024 * 2);
  unsigned short* pred = (unsigned short*)alloc((size_t)4096 * 512 * 2);

  // mailbox epoch reset (replay safety): must precede lstm_seq on this stream
  (void)hipMemsetAsync(mb0, 0, (size_t)257 * 8192 * 4, stream);
  (void)hipMemsetAsync(mb1, 0, (size_t)257 * 8192 * 4, stream);

  // fused weight transposes (fp32 -> bf16, (K,N) -> (N,K)): 6 jobs, one dispatch
  transpose_all<<<20608, 256, 0, stream>>>(Wp, WpT, Wc, WcT, Wih0, Wih0T, Whh0, Whh0T,
                                           Wih1, Whh1, W1T);

  embed_gather<<<4096, 128, 0, stream>>>(tok, emb, xbf);

  // G1: g0pre = x @ Wih0 + b0   (rows t*16+b, bf16 out)
  gemm_bt<1, 1, 0, 0><<<dim3(2048 / 128, 4096 / 128, 1), 256, 0, stream>>>(
      xbf, Wih0T, g0pre, b0, 512, 2048, 0, 0, 0);

  lstm_seq<<<64, 256, 0, stream>>>(g0pre, Whh0T, W1T, b1, mb0, mb1, out_a, cat);

  // outT[b][h][t]
  transpose_bf16<unsigned short><<<dim3(512 / 32, 256 / 32, 16), 256, 0, stream>>>(
      out_a, outT, 256, 512, 256, (long)256 * 512, (long)512 * 256);

  // scores[b][i][j] = out_i . out_j  (fp32)
  gemm_bt<0, 0, 0, 0><<<dim3(2, 2, 16), 256, 0, stream>>>(
      out_a, out_a, scores, nullptr, 512, 256, (long)256 * 512, (long)256 * 512, (long)256 * 256);

  softmax_w<<<1024, 256, 0, stream>>>(scores, tok, wT);

  // ctx[b][j][h] -> cat[:, :512] (bf16)
  gemm_bt<1, 0, 0, 0><<<dim3(4, 2, 16), 256, 0, stream>>>(
      wT, outT, cat, nullptr, 256, 1024, (long)256 * 256, (long)512 * 256, (long)256 * 1024);

  // pred = tanh(cat @ Wc + bc) (bf16)
  gemm_bt<1, 1, 1, 0><<<dim3(512 / 128, 4096 / 128, 1), 256, 0, stream>>>(
      cat, WcT, pred, bc, 1024, 512, 0, 0, 0);

  // logits = pred @ Wp + bp -> d_out (fp32, XCD-swizzled + coalesced epilogue)
  gemm_bt<0, 1, 0, 1><<<dim3(VV / 128, 4096 / 128, 1), 256, 0, stream>>>(
      pred, WpT, d_out, bp, 512, VV, 0, 0, 0);
}